// Round 15
// baseline (69.452 us; speedup 1.0000x reference)
//
#include <hip/hip_runtime.h>
#include <math.h>

#define EPS 1e-8f
#define MARGIN 0.5f
#define NEG_PER_WAVE 64
#define FIXSCALE 1048576.0f            // 2^20 fixed-point for t
#define MASK40 ((1ULL << 40) - 1)

typedef float    f4 __attribute__((ext_vector_type(4)));
typedef _Float16 h4 __attribute__((ext_vector_type(4)));

__device__ __forceinline__ float dot4(const f4 a, const f4 b) {
    return a.x * b.x + a.y * b.y + a.z * b.z + a.w * b.w;
}
__device__ __forceinline__ float dot4h(const h4 a, const f4 b) {
    return (float)a.x * b.x + (float)a.y * b.y + (float)a.z * b.z + (float)a.w * b.w;
}

// ============================ FP16-anchor path ==============================

// Kernel 1h: pos cosine + normalized fp16 anchor table + zero u64 accums.
__global__ void pos_h_kernel(const float* __restrict__ anchor,
                             const float* __restrict__ pos,
                             _Float16* __restrict__ a_h,
                             float* __restrict__ ps,
                             unsigned long long* __restrict__ acc,
                             int B) {
    const int tid  = blockIdx.x * blockDim.x + threadIdx.x;
    const int row  = tid >> 6;
    const int lane = threadIdx.x & 63;

    if (tid < 2 * B) ((unsigned int*)acc)[tid] = 0u;
    if (row >= B) return;

    const f4 a = *(reinterpret_cast<const f4*>(anchor + (size_t)row * 256) + lane);
    const f4 p = *(reinterpret_cast<const f4*>(pos    + (size_t)row * 256) + lane);

    float dot = dot4(a, p), na = dot4(a, a), nb = dot4(p, p);
    #pragma unroll
    for (int off = 32; off > 0; off >>= 1) {
        dot += __shfl_xor(dot, off);
        na  += __shfl_xor(na,  off);
        nb  += __shfl_xor(nb,  off);
    }
    const float sna   = sqrtf(na);
    const float scale = 1.0f / fmaxf(sna, 1e-20f);
    h4 ah;
    ah.x = (_Float16)(a.x * scale); ah.y = (_Float16)(a.y * scale);
    ah.z = (_Float16)(a.z * scale); ah.w = (_Float16)(a.w * scale);
    *(reinterpret_cast<h4*>(a_h + (size_t)row * 256) + lane) = ah;
    if (lane == 0) ps[row] = dot / fmaxf(sna * sqrtf(nb), EPS);
}

// Kernel 2h: R11 inner loop (16-lane groups, proven fastest) with
// NEG_PER_WAVE=64 — halves all per-wave fixed costs (idx hoist, flush,
// tail) and gives each wave a 64 KB sequential stream span. 4096 waves
// (16/CU) still ample TLP (ILP/TLP levers previously null).
__global__ void __launch_bounds__(256) neg_h_kernel(
        const _Float16* __restrict__ a_h,
        const float* __restrict__ neg,
        const int*  __restrict__ idx,
        const float* __restrict__ ps,
        unsigned long long* __restrict__ acc,
        int N) {
    __shared__ float ssim[4][NEG_PER_WAVE];

    const int lane  = threadIdx.x & 63;
    const int wid   = threadIdx.x >> 6;
    const int group = lane >> 4;
    const int glane = lane & 15;
    const long long base =
        ((long long)blockIdx.x * (blockDim.x >> 6) + wid) * NEG_PER_WAVE;

    // hoisted index load: all 64 lanes fetch this wave's 64 indices (256 B)
    int b_all = 0;
    {
        const long long in = base + lane;
        if (in < N) b_all = idx[in];
    }

    if (base < N) {
        const bool full = (base + NEG_PER_WAVE) <= N;
        #pragma unroll 2
        for (int it = 0; it < NEG_PER_WAVE; it += 4) {
            const long long n = base + it + group;
            const bool valid = full || (n < N);
            const long long ns = valid ? n : (long long)0;
            const int b = __shfl(b_all, it + group);   // register broadcast

            const f4* nr = reinterpret_cast<const f4*>(neg + (size_t)ns * 256);
            const h4* ar = reinterpret_cast<const h4*>(a_h + (size_t)b * 256);

            const f4 v0 = nr[ 0 + glane], v1 = nr[16 + glane],
                     v2 = nr[32 + glane], v3 = nr[48 + glane];
            const h4 a0 = ar[ 0 + glane], a1 = ar[16 + glane],
                     a2 = ar[32 + glane], a3 = ar[48 + glane];

            float d = dot4h(a0, v0) + dot4h(a1, v1) + dot4h(a2, v2) + dot4h(a3, v3);
            float q = dot4(v0, v0) + dot4(v1, v1) + dot4(v2, v2) + dot4(v3, v3);

            #pragma unroll
            for (int off = 8; off > 0; off >>= 1) {
                d += __shfl_xor(d, off);
                q += __shfl_xor(q, off);
            }
            if (glane == 0 && valid)
                ssim[wid][it + group] = d * rsqrtf(fmaxf(q, 1e-30f));
        }
    }

    // wave-local flush: lane L owns negative base+L; b is lane's own b_all.
    if (base + lane < N) {
        const float t = fmaxf(MARGIN + ssim[wid][lane] - ps[b_all], 0.0f);
        const unsigned long long pk =
            (unsigned long long)(t * FIXSCALE + 0.5f) + (1ULL << 40);
        atomicAdd(&acc[b_all], pk);
    }
}

// Kernel 3h: unpack u64 accums -> segment means -> scalar (one block).
__global__ void __launch_bounds__(1024) finalize_packed_kernel(
        const unsigned long long* __restrict__ acc,
        float* __restrict__ out, int B) {
    float local = 0.0f;
    for (int i = threadIdx.x; i < B; i += blockDim.x) {
        const unsigned long long v = acc[i];
        const float c = (float)(v >> 40);
        const float s = (float)(v & MASK40) * (1.0f / FIXSCALE);
        local += (c > 0.0f) ? (s / c) : 0.0f;
    }
    #pragma unroll
    for (int off = 32; off > 0; off >>= 1)
        local += __shfl_xor(local, off);

    __shared__ float ws[16];
    const int wid = threadIdx.x >> 6;
    if ((threadIdx.x & 63) == 0) ws[wid] = local;
    __syncthreads();
    if (threadIdx.x == 0) {
        float tot = 0.0f;
        const int nw = blockDim.x >> 6;
        for (int w = 0; w < nw; ++w) tot += ws[w];
        out[0] = tot / (float)B;
    }
}

// ===================== Fallback (fp32, known-good) ==========================

__global__ void pos_sim_kernel(const float* __restrict__ anchor,
                               const float* __restrict__ pos,
                               float2* __restrict__ pn,
                               float* __restrict__ sums,
                               float* __restrict__ counts,
                               int B) {
    const int tid  = blockIdx.x * blockDim.x + threadIdx.x;
    const int wave = tid >> 6;
    const int lane = threadIdx.x & 63;
    if (tid < B) sums[tid] = 0.0f;
    else if (tid < 2 * B) counts[tid - B] = 0.0f;
    if (wave >= B) return;
    const f4 a = *(reinterpret_cast<const f4*>(anchor + (size_t)wave * 256) + lane);
    const f4 p = *(reinterpret_cast<const f4*>(pos    + (size_t)wave * 256) + lane);
    float dot = dot4(a, p), na = dot4(a, a), nb = dot4(p, p);
    #pragma unroll
    for (int off = 32; off > 0; off >>= 1) {
        dot += __shfl_xor(dot, off);
        na  += __shfl_xor(na,  off);
        nb  += __shfl_xor(nb,  off);
    }
    if (lane == 0) {
        float sna = sqrtf(na);
        float2 r; r.x = dot / fmaxf(sna * sqrtf(nb), EPS); r.y = sna;
        pn[wave] = r;
    }
}

__global__ void __launch_bounds__(256) neg_kernel(
        const float* __restrict__ anchor,
        const float* __restrict__ neg,
        const int*  __restrict__ idx,
        const float2* __restrict__ pn,
        float* __restrict__ sums,
        float* __restrict__ counts,
        int N) {
    const int lane  = threadIdx.x & 63;
    const int wid   = threadIdx.x >> 6;
    const int group = lane >> 4;
    const int glane = lane & 15;
    const long long base =
        ((long long)blockIdx.x * (blockDim.x >> 6) + wid) * NEG_PER_WAVE;
    if (base >= N) return;
    for (int it = 0; it < NEG_PER_WAVE; it += 4) {
        const long long n = base + it + group;
        if (n >= N) continue;
        const int b = idx[n];
        const f4* ar = reinterpret_cast<const f4*>(anchor + (size_t)b * 256);
        const f4* nr = reinterpret_cast<const f4*>(neg + (size_t)n * 256);
        float d = 0.0f, q = 0.0f;
        #pragma unroll
        for (int c = 0; c < 4; ++c) {
            const f4 a = ar[c * 16 + glane];
            const f4 v = nr[c * 16 + glane];
            d += dot4(a, v); q += dot4(v, v);
        }
        #pragma unroll
        for (int off = 8; off > 0; off >>= 1) {
            d += __shfl_xor(d, off);
            q += __shfl_xor(q, off);
        }
        if (glane == 0) {
            const float2 p = pn[b];
            float t = fmaxf(MARGIN + d / fmaxf(p.y * sqrtf(q), EPS) - p.x, 0.0f);
            atomicAdd(&sums[b], t);
            atomicAdd(&counts[b], 1.0f);
        }
    }
}

__global__ void __launch_bounds__(1024) finalize_kernel(
        const float* __restrict__ sums,
        const float* __restrict__ counts,
        float* __restrict__ out, int B) {
    float local = 0.0f;
    for (int i = threadIdx.x; i < B; i += blockDim.x) {
        float c = counts[i];
        local += (c > 0.0f) ? (sums[i] / c) : 0.0f;
    }
    #pragma unroll
    for (int off = 32; off > 0; off >>= 1)
        local += __shfl_xor(local, off);

    __shared__ float ws[16];
    const int wid = threadIdx.x >> 6;
    if ((threadIdx.x & 63) == 0) ws[wid] = local;
    __syncthreads();
    if (threadIdx.x == 0) {
        float tot = 0.0f;
        const int nw = blockDim.x >> 6;
        for (int w = 0; w < nw; ++w) tot += ws[w];
        out[0] = tot / (float)B;
    }
}

extern "C" void kernel_launch(void* const* d_in, const int* in_sizes, int n_in,
                              void* d_out, int out_size, void* d_ws, size_t ws_size,
                              hipStream_t stream) {
    const float* anchor = (const float*)d_in[0];
    const float* pos    = (const float*)d_in[1];
    const float* neg    = (const float*)d_in[2];
    const int*   idx    = (const int*)d_in[3];

    const int D = 256;
    int B = in_sizes[0] / D;   // 4096
    int N = in_sizes[3];       // 262144

    const size_t need_h = (size_t)B * 256 * sizeof(_Float16)            // a_h
                        + (size_t)B * sizeof(float)                     // ps
                        + (size_t)B * sizeof(unsigned long long);       // acc

    const int threads = 256;
    const int negs_per_block = (threads / 64) * NEG_PER_WAVE;           // 256
    const int nblocks = (N + negs_per_block - 1) / negs_per_block;      // 1024

    if (ws_size >= need_h) {
        _Float16*           a_h = (_Float16*)d_ws;
        float*              ps  = (float*)(a_h + (size_t)B * 256);
        unsigned long long* acc = (unsigned long long*)(ps + B);

        pos_h_kernel<<<(B + 3) / 4, threads, 0, stream>>>(anchor, pos, a_h, ps,
                                                          acc, B);
        neg_h_kernel<<<nblocks, threads, 0, stream>>>(a_h, neg, idx, ps,
                                                      acc, N);
        finalize_packed_kernel<<<1, 1024, 0, stream>>>(acc, (float*)d_out, B);
    } else {
        // fallback: known-good fp32 path
        float2* pn     = (float2*)d_ws;
        float*  sums   = (float*)(pn + B);
        float*  counts = sums + B;

        pos_sim_kernel<<<(B + 3) / 4, threads, 0, stream>>>(anchor, pos, pn,
                                                            sums, counts, B);
        neg_kernel<<<nblocks, threads, 0, stream>>>(anchor, neg, idx, pn,
                                                    sums, counts, N);
        finalize_kernel<<<1, 1024, 0, stream>>>(sums, counts, (float*)d_out, B);
    }
}

// Round 16
// 62.110 us; speedup vs baseline: 1.1182x; 1.1182x over previous
//
#include <hip/hip_runtime.h>
#include <math.h>

#define EPS 1e-8f
#define MARGIN 0.5f
#define NEG_PER_WAVE 32
#define FIXSCALE 1048576.0f            // 2^20 fixed-point for t
#define MASK40 ((1ULL << 40) - 1)

typedef float    f4 __attribute__((ext_vector_type(4)));
typedef _Float16 h4 __attribute__((ext_vector_type(4)));

__device__ __forceinline__ float dot4(const f4 a, const f4 b) {
    return a.x * b.x + a.y * b.y + a.z * b.z + a.w * b.w;
}
__device__ __forceinline__ float dot4h(const h4 a, const f4 b) {
    return (float)a.x * b.x + (float)a.y * b.y + (float)a.z * b.z + (float)a.w * b.w;
}

// ============================ FP16-anchor path ==============================
// Best-known configuration (R11, 61.7 us): 8192 waves (32 negs/wave),
// 16-lane groups, unroll-2, hoisted idx, LDS-staged sims, one packed u64
// atomic per negative at wave end, separate 1-block finalize.

// Kernel 1h: pos cosine + normalized fp16 anchor table + zero u64 accums.
__global__ void pos_h_kernel(const float* __restrict__ anchor,
                             const float* __restrict__ pos,
                             _Float16* __restrict__ a_h,
                             float* __restrict__ ps,
                             unsigned long long* __restrict__ acc,
                             int B) {
    const int tid  = blockIdx.x * blockDim.x + threadIdx.x;
    const int row  = tid >> 6;
    const int lane = threadIdx.x & 63;

    if (tid < 2 * B) ((unsigned int*)acc)[tid] = 0u;
    if (row >= B) return;

    const f4 a = *(reinterpret_cast<const f4*>(anchor + (size_t)row * 256) + lane);
    const f4 p = *(reinterpret_cast<const f4*>(pos    + (size_t)row * 256) + lane);

    float dot = dot4(a, p), na = dot4(a, a), nb = dot4(p, p);
    #pragma unroll
    for (int off = 32; off > 0; off >>= 1) {
        dot += __shfl_xor(dot, off);
        na  += __shfl_xor(na,  off);
        nb  += __shfl_xor(nb,  off);
    }
    const float sna   = sqrtf(na);
    const float scale = 1.0f / fmaxf(sna, 1e-20f);
    h4 ah;
    ah.x = (_Float16)(a.x * scale); ah.y = (_Float16)(a.y * scale);
    ah.z = (_Float16)(a.z * scale); ah.w = (_Float16)(a.w * scale);
    *(reinterpret_cast<h4*>(a_h + (size_t)row * 256) + lane) = ah;
    if (lane == 0) ps[row] = dot / fmaxf(sna * sqrtf(nb), EPS);
}

// Kernel 2h: pure-stream hot loop; idx hoisted into registers (one coalesced
// 128 B load per wave, shfl-broadcast per step). One packed u64 atomic per
// negative, batched at wave end.
__global__ void __launch_bounds__(256) neg_h_kernel(
        const _Float16* __restrict__ a_h,
        const float* __restrict__ neg,
        const int*  __restrict__ idx,
        const float* __restrict__ ps,
        unsigned long long* __restrict__ acc,
        int N) {
    __shared__ float ssim[4][NEG_PER_WAVE];
    const int lane  = threadIdx.x & 63;
    const int wid   = threadIdx.x >> 6;
    const int group = lane >> 4;
    const int glane = lane & 15;
    const long long base =
        ((long long)blockIdx.x * (blockDim.x >> 6) + wid) * NEG_PER_WAVE;

    // hoisted index load: lanes 0..31 fetch this wave's 32 indices (128 B)
    int b_all = 0;
    {
        const long long in = base + lane;
        if (lane < NEG_PER_WAVE && in < N) b_all = idx[in];
    }

    if (base < N) {
        #pragma unroll 2
        for (int it = 0; it < NEG_PER_WAVE; it += 4) {
            const long long n = base + it + group;
            const bool valid = (n < N);
            const long long ns = valid ? n : (long long)0;
            const int b = __shfl(b_all, it + group);   // register broadcast

            const f4* nr = reinterpret_cast<const f4*>(neg + (size_t)ns * 256);
            const h4* ar = reinterpret_cast<const h4*>(a_h + (size_t)b * 256);

            const f4 v0 = nr[ 0 + glane], v1 = nr[16 + glane],
                     v2 = nr[32 + glane], v3 = nr[48 + glane];
            const h4 a0 = ar[ 0 + glane], a1 = ar[16 + glane],
                     a2 = ar[32 + glane], a3 = ar[48 + glane];

            float d = dot4h(a0, v0) + dot4h(a1, v1) + dot4h(a2, v2) + dot4h(a3, v3);
            float q = dot4(v0, v0) + dot4(v1, v1) + dot4(v2, v2) + dot4(v3, v3);

            #pragma unroll
            for (int off = 8; off > 0; off >>= 1) {
                d += __shfl_xor(d, off);
                q += __shfl_xor(q, off);
            }
            if (glane == 0 && valid)
                ssim[wid][it + group] = d * rsqrtf(fmaxf(q, 1e-30f));
        }
    }

    // wave-local flush: lane L owns negative base+L; b is lane's own b_all.
    if (lane < NEG_PER_WAVE && base + lane < N) {
        const float t = fmaxf(MARGIN + ssim[wid][lane] - ps[b_all], 0.0f);
        const unsigned long long pk =
            (unsigned long long)(t * FIXSCALE + 0.5f) + (1ULL << 40);
        atomicAdd(&acc[b_all], pk);
    }
}

// Kernel 3h: unpack u64 accums -> segment means -> scalar (one block).
__global__ void __launch_bounds__(1024) finalize_packed_kernel(
        const unsigned long long* __restrict__ acc,
        float* __restrict__ out, int B) {
    float local = 0.0f;
    for (int i = threadIdx.x; i < B; i += blockDim.x) {
        const unsigned long long v = acc[i];
        const float c = (float)(v >> 40);
        const float s = (float)(v & MASK40) * (1.0f / FIXSCALE);
        local += (c > 0.0f) ? (s / c) : 0.0f;
    }
    #pragma unroll
    for (int off = 32; off > 0; off >>= 1)
        local += __shfl_xor(local, off);

    __shared__ float ws[16];
    const int wid = threadIdx.x >> 6;
    if ((threadIdx.x & 63) == 0) ws[wid] = local;
    __syncthreads();
    if (threadIdx.x == 0) {
        float tot = 0.0f;
        const int nw = blockDim.x >> 6;
        for (int w = 0; w < nw; ++w) tot += ws[w];
        out[0] = tot / (float)B;
    }
}

// ===================== Fallback (fp32, known-good) ==========================

__global__ void pos_sim_kernel(const float* __restrict__ anchor,
                               const float* __restrict__ pos,
                               float2* __restrict__ pn,
                               float* __restrict__ sums,
                               float* __restrict__ counts,
                               int B) {
    const int tid  = blockIdx.x * blockDim.x + threadIdx.x;
    const int wave = tid >> 6;
    const int lane = threadIdx.x & 63;
    if (tid < B) sums[tid] = 0.0f;
    else if (tid < 2 * B) counts[tid - B] = 0.0f;
    if (wave >= B) return;
    const f4 a = *(reinterpret_cast<const f4*>(anchor + (size_t)wave * 256) + lane);
    const f4 p = *(reinterpret_cast<const f4*>(pos    + (size_t)wave * 256) + lane);
    float dot = dot4(a, p), na = dot4(a, a), nb = dot4(p, p);
    #pragma unroll
    for (int off = 32; off > 0; off >>= 1) {
        dot += __shfl_xor(dot, off);
        na  += __shfl_xor(na,  off);
        nb  += __shfl_xor(nb,  off);
    }
    if (lane == 0) {
        float sna = sqrtf(na);
        float2 r; r.x = dot / fmaxf(sna * sqrtf(nb), EPS); r.y = sna;
        pn[wave] = r;
    }
}

__global__ void __launch_bounds__(256) neg_kernel(
        const float* __restrict__ anchor,
        const float* __restrict__ neg,
        const int*  __restrict__ idx,
        const float2* __restrict__ pn,
        float* __restrict__ sums,
        float* __restrict__ counts,
        int N) {
    const int lane  = threadIdx.x & 63;
    const int wid   = threadIdx.x >> 6;
    const int group = lane >> 4;
    const int glane = lane & 15;
    const long long base =
        ((long long)blockIdx.x * (blockDim.x >> 6) + wid) * NEG_PER_WAVE;
    if (base >= N) return;
    for (int it = 0; it < NEG_PER_WAVE; it += 4) {
        const long long n = base + it + group;
        if (n >= N) continue;
        const int b = idx[n];
        const f4* ar = reinterpret_cast<const f4*>(anchor + (size_t)b * 256);
        const f4* nr = reinterpret_cast<const f4*>(neg + (size_t)n * 256);
        float d = 0.0f, q = 0.0f;
        #pragma unroll
        for (int c = 0; c < 4; ++c) {
            const f4 a = ar[c * 16 + glane];
            const f4 v = nr[c * 16 + glane];
            d += dot4(a, v); q += dot4(v, v);
        }
        #pragma unroll
        for (int off = 8; off > 0; off >>= 1) {
            d += __shfl_xor(d, off);
            q += __shfl_xor(q, off);
        }
        if (glane == 0) {
            const float2 p = pn[b];
            float t = fmaxf(MARGIN + d / fmaxf(p.y * sqrtf(q), EPS) - p.x, 0.0f);
            atomicAdd(&sums[b], t);
            atomicAdd(&counts[b], 1.0f);
        }
    }
}

__global__ void __launch_bounds__(1024) finalize_kernel(
        const float* __restrict__ sums,
        const float* __restrict__ counts,
        float* __restrict__ out, int B) {
    float local = 0.0f;
    for (int i = threadIdx.x; i < B; i += blockDim.x) {
        float c = counts[i];
        local += (c > 0.0f) ? (sums[i] / c) : 0.0f;
    }
    #pragma unroll
    for (int off = 32; off > 0; off >>= 1)
        local += __shfl_xor(local, off);

    __shared__ float ws[16];
    const int wid = threadIdx.x >> 6;
    if ((threadIdx.x & 63) == 0) ws[wid] = local;
    __syncthreads();
    if (threadIdx.x == 0) {
        float tot = 0.0f;
        const int nw = blockDim.x >> 6;
        for (int w = 0; w < nw; ++w) tot += ws[w];
        out[0] = tot / (float)B;
    }
}

extern "C" void kernel_launch(void* const* d_in, const int* in_sizes, int n_in,
                              void* d_out, int out_size, void* d_ws, size_t ws_size,
                              hipStream_t stream) {
    const float* anchor = (const float*)d_in[0];
    const float* pos    = (const float*)d_in[1];
    const float* neg    = (const float*)d_in[2];
    const int*   idx    = (const int*)d_in[3];

    const int D = 256;
    int B = in_sizes[0] / D;   // 4096
    int N = in_sizes[3];       // 262144

    const size_t need_h = (size_t)B * 256 * sizeof(_Float16)            // a_h
                        + (size_t)B * sizeof(float)                     // ps
                        + (size_t)B * sizeof(unsigned long long);       // acc

    const int threads = 256;
    const int negs_per_block = (threads / 64) * NEG_PER_WAVE;           // 128
    const int nblocks = (N + negs_per_block - 1) / negs_per_block;      // 2048

    if (ws_size >= need_h) {
        _Float16*           a_h = (_Float16*)d_ws;
        float*              ps  = (float*)(a_h + (size_t)B * 256);
        unsigned long long* acc = (unsigned long long*)(ps + B);

        pos_h_kernel<<<(B + 3) / 4, threads, 0, stream>>>(anchor, pos, a_h, ps,
                                                          acc, B);
        neg_h_kernel<<<nblocks, threads, 0, stream>>>(a_h, neg, idx, ps,
                                                      acc, N);
        finalize_packed_kernel<<<1, 1024, 0, stream>>>(acc, (float*)d_out, B);
    } else {
        // fallback: known-good fp32 path
        float2* pn     = (float2*)d_ws;
        float*  sums   = (float*)(pn + B);
        float*  counts = sums + B;

        pos_sim_kernel<<<(B + 3) / 4, threads, 0, stream>>>(anchor, pos, pn,
                                                            sums, counts, B);
        neg_kernel<<<nblocks, threads, 0, stream>>>(anchor, neg, idx, pn,
                                                    sums, counts, N);
        finalize_kernel<<<1, 1024, 0, stream>>>(sums, counts, (float*)d_out, B);
    }
}